// Round 4
// baseline (42883.765 us; speedup 1.0000x reference)
//
#include <hip/hip_runtime.h>

// LSTM T=512,B=128,D=H=1024. R4: persistent cooperative kernel (R3 structure)
// with hardened cross-XCD h-exchange: SYSTEM-scope write-through h stores,
// all-thread SYSTEM-acquire spin, system fence before release increment.
// 256 blocks (1/CU), 512 thr (8 waves). Block tile: 64 batch rows (rg=bid>>7)
// x 32 gate-cols (cg=bid&127). W bf16 resident in LDS (128 KiB, XOR-swizzled),
// A-chunks (x|h) double-buffered 2x16 KiB -> 160 KiB LDS total. c in registers.
// Gate interleave: gate-col n = hcol*4+gate -> f/i/g/o in lanes l^{0,1,2,3}.

#define TT 512
#define BB 128

typedef __attribute__((ext_vector_type(8))) short short8;
typedef __attribute__((ext_vector_type(4))) float f32x4;

// persistent-path ws layout
#define WQ_BYTES   16777216                  // [4][1024][2048] bf16
#define XBF_OFF    WQ_BYTES
#define XBF_BYTES  134217728                 // [512][128][1024] bf16
#define HBUF_OFF   (XBF_OFF + XBF_BYTES)
#define HBUF_BYTES 524288                    // 2 x [128][1024] bf16
#define CNT_OFF    (HBUF_OFF + HBUF_BYTES)
#define WS_NEED    ((size_t)CNT_OFF + 4096)

__device__ __forceinline__ unsigned short f2bf(float x) {
    union { float f; unsigned int u; } a; a.f = x;
    unsigned int r = a.u + 0x7fff + ((a.u >> 16) & 1);
    return (unsigned short)(r >> 16);
}

__device__ __forceinline__ float sigmoidf_(float x) {
    return 1.0f / (1.0f + expf(-x));
}

__device__ __forceinline__ void gll16(const void* g, void* l) {
    __builtin_amdgcn_global_load_lds(
        (const __attribute__((address_space(1))) unsigned int*)g,
        (__attribute__((address_space(3))) unsigned int*)l, 16, 0, 0);
}

// ---------------- conversion kernels ----------------

__global__ __launch_bounds__(256) void cvt_w(const float* __restrict__ Wf,
                                             const float* __restrict__ Wi,
                                             const float* __restrict__ Wg,
                                             const float* __restrict__ Wo,
                                             unsigned short* __restrict__ dst) {
    size_t i4 = (size_t)blockIdx.x * 256 + threadIdx.x;  // float4 index
    int g = (int)(i4 >> 19);                             // 524288 float4 per gate
    size_t off = (i4 & 524287) * 4;
    const float* src = (g == 0) ? Wf : (g == 1) ? Wi : (g == 2) ? Wg : Wo;
    float4 v = *(const float4*)(src + off);
    unsigned int lo = (unsigned)f2bf(v.x) | ((unsigned)f2bf(v.y) << 16);
    unsigned int hi = (unsigned)f2bf(v.z) | ((unsigned)f2bf(v.w) << 16);
    uint2 u; u.x = lo; u.y = hi;
    *(uint2*)(dst + (size_t)g * 2097152 + off) = u;
}

__global__ __launch_bounds__(256) void cvt_x(const float* __restrict__ X,
                                             unsigned short* __restrict__ dst) {
    size_t off = ((size_t)blockIdx.x * 256 + threadIdx.x) * 8;
    float4 a = *(const float4*)(X + off);
    float4 b = *(const float4*)(X + off + 4);
    uint4 u;
    u.x = (unsigned)f2bf(a.x) | ((unsigned)f2bf(a.y) << 16);
    u.y = (unsigned)f2bf(a.z) | ((unsigned)f2bf(a.w) << 16);
    u.z = (unsigned)f2bf(b.x) | ((unsigned)f2bf(b.y) << 16);
    u.w = (unsigned)f2bf(b.z) | ((unsigned)f2bf(b.w) << 16);
    *(uint4*)(dst + off) = u;
}

__global__ __launch_bounds__(256) void zero_ws(unsigned int* __restrict__ p) {
    p[blockIdx.x * 256 + threadIdx.x] = 0u;
}

// ---------------- persistent LSTM kernel ----------------

__global__ __launch_bounds__(512) void lstm_persist(
    const unsigned short* __restrict__ Xbf,  // [512][128][1024] bf16
    const unsigned short* __restrict__ Wq,   // [4][1024][2048] bf16
    const float* __restrict__ bfp, const float* __restrict__ bip,
    const float* __restrict__ bgp, const float* __restrict__ bop,
    unsigned short* __restrict__ hbuf,       // 2 x [128][1024] bf16
    unsigned* __restrict__ cnt,              // 16 sub-counters, stride 64 uints
    float* __restrict__ out) {
    extern __shared__ __align__(16) unsigned char smem[];
    unsigned char* Wl  = smem;            // 131072 B: 32 rows x 4096 B, swizzled
    unsigned char* Ab0 = smem + 131072;   // 16384 B: 64 rows x 256 B, swizzled
    unsigned char* Ab1 = smem + 147456;

    const int tid = threadIdx.x;
    const int l = tid & 63;
    const int w = tid >> 6;               // 0..7
    const int wr = w >> 1, wc = w & 1;
    const int rg = blockIdx.x >> 7;       // 0..1
    const int cg = blockIdx.x & 127;
    const int lq = l >> 4, sp = l & 15;
    const int g0 = l & 3;

    // ---- stage W into LDS (once): 16 rounds x 8 waves = 128 segs of 1 KiB ----
    for (int r = 0; r < 16; ++r) {
        const int seg = w * 16 + r;
        const int bn = seg >> 2, q = seg & 3;
        const unsigned short* src =
            Wq + ((size_t)((bn & 3) * 1024 + cg * 8 + (bn >> 2))) * 2048 +
            (size_t)((q * 64 + l) ^ (bn & 7)) * 8;
        gll16(src, Wl + seg * 1024);
    }

    // ---- A staging invariants (2 gll/thread/chunk, 16 segs of 1 KiB) ----
    const int row0 = (w * 2 + 0) * 4 + (l >> 4);
    const int row1 = (w * 2 + 1) * 4 + (l >> 4);
    const unsigned sw0 = (unsigned)(((l & 15) ^ (row0 & 7)) * 8);
    const unsigned sw1 = (unsigned)(((l & 15) ^ (row1 & 7)) * 8);
    const unsigned short* xb0 = Xbf + (size_t)(rg * 64 + row0) * 1024 + sw0;
    const unsigned short* xb1 = Xbf + (size_t)(rg * 64 + row1) * 1024 + sw1;
    const unsigned short* hb0 = hbuf + (size_t)(rg * 64 + row0) * 1024 + sw0;
    const unsigned short* hb1 = hbuf + (size_t)(rg * 64 + row1) * 1024 + sw1;
    const unsigned adst0 = (unsigned)((w * 2 + 0) * 1024);
    const unsigned adst1 = (unsigned)((w * 2 + 1) * 1024);

    auto issueA = [&](int c, unsigned char* buf, int t) {
        if (c < 8) {
            const size_t o = (size_t)t * 131072 + c * 128;
            gll16(xb0 + o, buf + adst0);
            gll16(xb1 + o, buf + adst1);
        } else {
            const size_t o = (size_t)((t + 1) & 1) * 131072 + (c - 8) * 128;
            gll16(hb0 + o, buf + adst0);
            gll16(hb1 + o, buf + adst1);
        }
    };

    // ---- compute invariants ----
    const int arow = wr * 16 + sp;
    const unsigned abase = (unsigned)(arow * 256), axor = (unsigned)((arow & 7) << 4);
    const int bn = wc * 16 + sp;
    const unsigned bbase = (unsigned)(bn * 4096), bxor = (unsigned)((bn & 7) << 4);

    // epilogue mapping
    const int j = cg * 8 + wc * 4 + (sp >> 2);
    const float biasv = (g0 == 0) ? bfp[j] : (g0 == 1) ? bip[j]
                      : (g0 == 2) ? bgp[j] : bop[j];
    const int rbase = rg * 64 + wr * 16 + lq * 4;

    float c4[4] = {0.f, 0.f, 0.f, 0.f};

    issueA(0, Ab0, 0);  // first x chunk of t=0 (in flight during W stage drain)

    for (int t = 0; t < TT; ++t) {
        if (t > 0) {
            // all threads spin: every wave gets its own SYSTEM-scope acquire
            const unsigned* p = cnt + (rg * 8 + (tid & 7)) * 64;
            const unsigned tgt = 16u * (unsigned)t;
            while (__hip_atomic_load(p, __ATOMIC_ACQUIRE, __HIP_MEMORY_SCOPE_SYSTEM) < tgt)
                __builtin_amdgcn_s_sleep(1);
        }
        __syncthreads();  // drains W-stage (t=0) + prefetched x chunk 0

        const int nch = (t == 0) ? 8 : 16;
        f32x4 acc_a = {biasv, biasv, biasv, biasv};
        f32x4 acc_b = {0.f, 0.f, 0.f, 0.f};

        for (int c = 0; c < nch; ++c) {
            unsigned char* cur = (c & 1) ? Ab1 : Ab0;
            unsigned char* nxt = (c & 1) ? Ab0 : Ab1;
            if (c + 1 < nch) issueA(c + 1, nxt, t);
#pragma unroll
            for (int ks = 0; ks < 4; ++ks) {
                const unsigned as = abase + (((unsigned)((ks * 4 + lq) << 4)) ^ axor);
                const unsigned bs = bbase + (((unsigned)((c * 16 + ks * 4 + lq) << 4)) ^ bxor);
                short8 a = *(const short8*)(cur + as);
                short8 b = *(const short8*)(Wl + bs);
                if (ks & 1) acc_b = __builtin_amdgcn_mfma_f32_16x16x32_bf16(a, b, acc_b, 0, 0, 0);
                else        acc_a = __builtin_amdgcn_mfma_f32_16x16x32_bf16(a, b, acc_a, 0, 0, 0);
            }
            __syncthreads();
        }

        // ---- epilogue: gate combine, c/h update, stores ----
        unsigned short* hnx = hbuf + (size_t)(t & 1) * 131072;
        f32x4 z4 = acc_a + acc_b;
#pragma unroll
        for (int r = 0; r < 4; ++r) {
            float z = z4[r];
            float v1 = __shfl_xor(z, 1);
            float v2 = __shfl_xor(z, 2);
            float v3 = __shfl_xor(z, 3);
            if (g0 == 0) {
                float fg = sigmoidf_(z);
                float ig = sigmoidf_(v1);
                float gg = tanhf(v2);
                float og = sigmoidf_(v3);
                float cc = fg * c4[r] + ig * gg;
                c4[r] = cc;
                float hh = og * tanhf(cc);
                const int row = rbase + r;
                const size_t idx = (size_t)row * 1024 + j;
                out[((size_t)t * BB + row) * 1024 + j] = hh;
                // write-through past non-coherent per-XCD L2 to coherence point
                __hip_atomic_store(&hnx[idx], f2bf(hh), __ATOMIC_RELAXED,
                                   __HIP_MEMORY_SCOPE_SYSTEM);
                if (t == TT - 1) {
                    out[(size_t)TT * BB * 1024 + idx] = hh;
                    out[(size_t)TT * BB * 1024 + (size_t)BB * 1024 + idx] = cc;
                }
            }
        }

        if (t < TT - 1) {
            __threadfence_system();  // h stores complete + visible everywhere
            __syncthreads();         // all threads fenced
            if (tid == 0)
                __hip_atomic_fetch_add(cnt + (rg * 8 + (cg & 7)) * 64, 1u,
                                       __ATOMIC_RELEASE, __HIP_MEMORY_SCOPE_SYSTEM);
            issueA(0, Ab0, t + 1);   // next step's x chunk 0 hides under spin
        }
    }
}

// ================= fallback path (R2, proven) =================

__device__ __forceinline__ unsigned aoff(int row, int k) {
    return (unsigned)(row * 256 + ((k * 2) ^ ((row & 7) << 4)));
}

__global__ __launch_bounds__(256) void lstm_step(
    const float* __restrict__ X, const unsigned short* __restrict__ Wq,
    const float* __restrict__ bfp, const float* __restrict__ bip,
    const float* __restrict__ bgp, const float* __restrict__ bop,
    const unsigned short* __restrict__ h_prev, unsigned short* __restrict__ h_next,
    float* __restrict__ c_ws, float* __restrict__ out, int t) {
    __shared__ __align__(16) unsigned char smem[32768];
    const int tid = threadIdx.x;
    const int l = tid & 63;
    const int w = tid >> 6;
    const int wr = w >> 1, wc = w & 1;
    const int rg = blockIdx.x >> 7;
    const int cg = blockIdx.x & 127;
    const int lq = l >> 4;
    const int sp = l & 15;
    const int g0 = l & 3;
    const int j = cg * 8 + wc * 4 + (sp >> 2);
    const float biasv = (g0 == 0) ? bfp[j] : (g0 == 1) ? bip[j]
                      : (g0 == 2) ? bgp[j] : bop[j];
    f32x4 acc_a = {biasv, biasv, biasv, biasv};
    f32x4 acc_b = {0.f, 0.f, 0.f, 0.f};
    const int bn0 = w * 8 + lq, bn1 = bn0 + 4;
    const unsigned short* wsrc0 =
        Wq + ((size_t)((bn0 & 3) * 1024 + cg * 8 + (bn0 >> 2))) * 2048 + (sp ^ (bn0 & 7)) * 8;
    const unsigned short* wsrc1 =
        Wq + ((size_t)((bn1 & 3) * 1024 + cg * 8 + (bn1 >> 2))) * 2048 + (sp ^ (bn1 & 7)) * 8;
    const unsigned short* hsrc0 = h_prev + (size_t)(rg * 32 + bn0) * 1024 + (sp ^ (bn0 & 7)) * 8;
    const unsigned short* hsrc1 = h_prev + (size_t)(rg * 32 + bn1) * 1024 + (sp ^ (bn1 & 7)) * 8;
    const int xrow = tid >> 3;
    const int xs = (tid & 7) * 2;
    const float* xsrc = X + ((size_t)t * BB + rg * 32 + xrow) * 1024 + xs * 8;
    const unsigned xw0 = (unsigned)(xrow * 256 + ((xs * 16) ^ ((xrow & 7) << 4)));
    const unsigned xw1 = (unsigned)(xrow * 256 + (((xs + 1) * 16) ^ ((xrow & 7) << 4)));
    float4 xv0, xv1, xv2, xv3;
    auto load_x = [&](int c) {
        const float* p = xsrc + c * 128;
        xv0 = *(const float4*)(p); xv1 = *(const float4*)(p + 4);
        xv2 = *(const float4*)(p + 8); xv3 = *(const float4*)(p + 12);
    };
    auto write_x = [&](int buf) {
        unsigned char* Ab = smem + (buf ? 8192 : 0);
        uint4 u0, u1;
        u0.x = (unsigned)f2bf(xv0.x) | ((unsigned)f2bf(xv0.y) << 16);
        u0.y = (unsigned)f2bf(xv0.z) | ((unsigned)f2bf(xv0.w) << 16);
        u0.z = (unsigned)f2bf(xv1.x) | ((unsigned)f2bf(xv1.y) << 16);
        u0.w = (unsigned)f2bf(xv1.z) | ((unsigned)f2bf(xv1.w) << 16);
        u1.x = (unsigned)f2bf(xv2.x) | ((unsigned)f2bf(xv2.y) << 16);
        u1.y = (unsigned)f2bf(xv2.z) | ((unsigned)f2bf(xv2.w) << 16);
        u1.z = (unsigned)f2bf(xv3.x) | ((unsigned)f2bf(xv3.y) << 16);
        u1.w = (unsigned)f2bf(xv3.z) | ((unsigned)f2bf(xv3.w) << 16);
        *(uint4*)(Ab + xw0) = u0; *(uint4*)(Ab + xw1) = u1;
    };
    auto stage_B = [&](int c, int buf) {
        unsigned char* Bb = smem + 16384 + (buf ? 8192 : 0);
        gll16(wsrc0 + c * 128, Bb + (w * 8) * 256);
        gll16(wsrc1 + c * 128, Bb + (w * 8 + 4) * 256);
    };
    auto stage_Ah = [&](int c, int buf) {
        unsigned char* Ab = smem + (buf ? 8192 : 0);
        gll16(hsrc0 + c * 128 - 1024, Ab + (w * 8) * 256);
        gll16(hsrc1 + c * 128 - 1024, Ab + (w * 8 + 4) * 256);
    };
    auto compute = [&](int buf) {
        const unsigned char* Ab = smem + (buf ? 8192 : 0);
        const unsigned char* Bb = smem + 16384 + (buf ? 8192 : 0);
        const int ar = wr * 16 + sp;
        const int br = wc * 16 + sp;
#pragma unroll
        for (int ks = 0; ks < 4; ++ks) {
            const int kk = ks * 32 + lq * 8;
            short8 a = *(const short8*)(Ab + aoff(ar, kk));
            short8 b = *(const short8*)(Bb + aoff(br, kk));
            if (ks & 1) acc_b = __builtin_amdgcn_mfma_f32_16x16x32_bf16(a, b, acc_b, 0, 0, 0);
            else        acc_a = __builtin_amdgcn_mfma_f32_16x16x32_bf16(a, b, acc_a, 0, 0, 0);
        }
    };
    load_x(0); stage_B(0, 0); write_x(0);
    __syncthreads();
    for (int c = 0; c < 16; ++c) {
        const int buf = c & 1, nbuf = buf ^ 1;
        const int nx = c + 1;
        if (c < 15) {
            if (nx < 8) load_x(nx);
            stage_B(nx, nbuf);
            if (nx >= 8) stage_Ah(nx, nbuf);
        }
        compute(buf);
        if (c < 15 && nx < 8) write_x(nbuf);
        __syncthreads();
    }
    f32x4 z4 = acc_a + acc_b;
    const int rbase = rg * 32 + wr * 16 + lq * 4;
#pragma unroll
    for (int r = 0; r < 4; ++r) {
        float z = z4[r];
        float v1 = __shfl_xor(z, 1);
        float v2 = __shfl_xor(z, 2);
        float v3 = __shfl_xor(z, 3);
        if (g0 == 0) {
            float fg = sigmoidf_(z), ig = sigmoidf_(v1);
            float gg = tanhf(v2), og = sigmoidf_(v3);
            const int row = rbase + r;
            const size_t idx = (size_t)row * 1024 + j;
            float cc = fg * c_ws[idx] + ig * gg;
            c_ws[idx] = cc;
            float hh = og * tanhf(cc);
            out[((size_t)t * BB + row) * 1024 + j] = hh;
            h_next[idx] = f2bf(hh);
            if (t == TT - 1) {
                out[(size_t)TT * BB * 1024 + idx] = hh;
                out[(size_t)TT * BB * 1024 + (size_t)BB * 1024 + idx] = cc;
            }
        }
    }
}

// ---------------- host ----------------

extern "C" void kernel_launch(void* const* d_in, const int* in_sizes, int n_in,
                              void* d_out, int out_size, void* d_ws, size_t ws_size,
                              hipStream_t stream) {
    const float* X  = (const float*)d_in[0];
    const float* Wf = (const float*)d_in[1];
    const float* bf = (const float*)d_in[2];
    const float* Wi = (const float*)d_in[3];
    const float* bi = (const float*)d_in[4];
    const float* Wg = (const float*)d_in[5];
    const float* bg = (const float*)d_in[6];
    const float* Wo = (const float*)d_in[7];
    const float* bo = (const float*)d_in[8];
    unsigned char* ws = (unsigned char*)d_ws;

    if (ws_size >= WS_NEED) {
        unsigned short* Wq = (unsigned short*)ws;
        unsigned short* Xb = (unsigned short*)(ws + XBF_OFF);
        unsigned short* hb = (unsigned short*)(ws + HBUF_OFF);
        unsigned* cnt = (unsigned*)(ws + CNT_OFF);
        float* outp = (float*)d_out;

        cvt_w<<<dim3(8192), dim3(256), 0, stream>>>(Wf, Wi, Wg, Wo, Wq);
        cvt_x<<<dim3(32768), dim3(256), 0, stream>>>(X, Xb);
        hipMemsetAsync(cnt, 0, 4096, stream);
        hipFuncSetAttribute((const void*)lstm_persist,
                            hipFuncAttributeMaxDynamicSharedMemorySize, 163840);

        const unsigned short* XbC = Xb;
        const unsigned short* WqC = Wq;
        void* args[] = {(void*)&XbC, (void*)&WqC, (void*)&bf, (void*)&bi,
                        (void*)&bg, (void*)&bo, (void*)&hb, (void*)&cnt, (void*)&outp};
        hipLaunchCooperativeKernel((const void*)lstm_persist, dim3(256), dim3(512),
                                   args, 163840, stream);
    } else {
        unsigned short* Wq = (unsigned short*)ws;
        unsigned short* hbuf = (unsigned short*)(ws + 16777216);
        float* c_ws = (float*)(ws + 16777216 + 524288);
        cvt_w<<<dim3(8192), dim3(256), 0, stream>>>(Wf, Wi, Wg, Wo, Wq);
        zero_ws<<<dim3(1024), dim3(256), 0, stream>>>((unsigned int*)(ws + 16777216));
        for (int t = 0; t < TT; ++t) {
            const unsigned short* hp = hbuf + (size_t)(t & 1) * (BB * 1024);
            unsigned short* hn = hbuf + (size_t)((t + 1) & 1) * (BB * 1024);
            lstm_step<<<dim3(512), dim3(256), 0, stream>>>(
                X, Wq, bf, bi, bg, bo, hp, hn, c_ws, (float*)d_out, t);
        }
    }
}

// Round 5
// 15839.357 us; speedup vs baseline: 2.7074x; 2.7074x over previous
//
#include <hip/hip_runtime.h>

// LSTM T=512,B=128,D=H=1024. R5: persistent cooperative kernel (R4 structure)
// with AGENT-scope sync: wave0 relaxed spin + per-wave acquire fence,
// coalesced 8B agent write-through h stores (4x4 shuffle transpose),
// float4 out stores. 256 blocks (1/CU), 512 thr (8 waves).
// W bf16 in LDS (128 KiB, XOR-swizzled), A-chunks double-buffered 2x16 KiB.
// Gate interleave: gate-col n = hcol*4+gate -> f/i/g/o in lanes l^{0,1,2,3}.

#define TT 512
#define BB 128

typedef __attribute__((ext_vector_type(8))) short short8;
typedef __attribute__((ext_vector_type(4))) float f32x4;

// persistent-path ws layout
#define WQ_BYTES   16777216                  // [4][1024][2048] bf16
#define XBF_OFF    WQ_BYTES
#define XBF_BYTES  134217728                 // [512][128][1024] bf16
#define HBUF_OFF   (XBF_OFF + XBF_BYTES)
#define HBUF_BYTES 524288                    // 2 x [128][1024] bf16
#define CNT_OFF    (HBUF_OFF + HBUF_BYTES)
#define WS_NEED    ((size_t)CNT_OFF + 4096)

__device__ __forceinline__ unsigned short f2bf(float x) {
    union { float f; unsigned int u; } a; a.f = x;
    unsigned int r = a.u + 0x7fff + ((a.u >> 16) & 1);
    return (unsigned short)(r >> 16);
}

__device__ __forceinline__ float sigmoidf_(float x) {
    return 1.0f / (1.0f + expf(-x));
}

__device__ __forceinline__ void gll16(const void* g, void* l) {
    __builtin_amdgcn_global_load_lds(
        (const __attribute__((address_space(1))) unsigned int*)g,
        (__attribute__((address_space(3))) unsigned int*)l, 16, 0, 0);
}

// ---------------- conversion kernels ----------------

__global__ __launch_bounds__(256) void cvt_w(const float* __restrict__ Wf,
                                             const float* __restrict__ Wi,
                                             const float* __restrict__ Wg,
                                             const float* __restrict__ Wo,
                                             unsigned short* __restrict__ dst) {
    size_t i4 = (size_t)blockIdx.x * 256 + threadIdx.x;  // float4 index
    int g = (int)(i4 >> 19);                             // 524288 float4 per gate
    size_t off = (i4 & 524287) * 4;
    const float* src = (g == 0) ? Wf : (g == 1) ? Wi : (g == 2) ? Wg : Wo;
    float4 v = *(const float4*)(src + off);
    unsigned int lo = (unsigned)f2bf(v.x) | ((unsigned)f2bf(v.y) << 16);
    unsigned int hi = (unsigned)f2bf(v.z) | ((unsigned)f2bf(v.w) << 16);
    uint2 u; u.x = lo; u.y = hi;
    *(uint2*)(dst + (size_t)g * 2097152 + off) = u;
}

__global__ __launch_bounds__(256) void cvt_x(const float* __restrict__ X,
                                             unsigned short* __restrict__ dst) {
    size_t off = ((size_t)blockIdx.x * 256 + threadIdx.x) * 8;
    float4 a = *(const float4*)(X + off);
    float4 b = *(const float4*)(X + off + 4);
    uint4 u;
    u.x = (unsigned)f2bf(a.x) | ((unsigned)f2bf(a.y) << 16);
    u.y = (unsigned)f2bf(a.z) | ((unsigned)f2bf(a.w) << 16);
    u.z = (unsigned)f2bf(b.x) | ((unsigned)f2bf(b.y) << 16);
    u.w = (unsigned)f2bf(b.z) | ((unsigned)f2bf(b.w) << 16);
    *(uint4*)(dst + off) = u;
}

__global__ __launch_bounds__(256) void zero_ws(unsigned int* __restrict__ p) {
    p[blockIdx.x * 256 + threadIdx.x] = 0u;
}

// ---------------- persistent LSTM kernel ----------------

__global__ __launch_bounds__(512) void lstm_persist(
    const unsigned short* __restrict__ Xbf,  // [512][128][1024] bf16
    const unsigned short* __restrict__ Wq,   // [4][1024][2048] bf16
    const float* __restrict__ bfp, const float* __restrict__ bip,
    const float* __restrict__ bgp, const float* __restrict__ bop,
    unsigned short* __restrict__ hbuf,       // 2 x [128][1024] bf16
    unsigned* __restrict__ cnt,              // 16 sub-counters, stride 64 uints
    float* __restrict__ out) {
    extern __shared__ __align__(16) unsigned char smem[];
    unsigned char* Wl  = smem;            // 131072 B: 32 rows x 4096 B, swizzled
    unsigned char* Ab0 = smem + 131072;   // 16384 B: 64 rows x 256 B, swizzled
    unsigned char* Ab1 = smem + 147456;

    const int tid = threadIdx.x;
    const int l = tid & 63;
    const int w = tid >> 6;               // 0..7
    const int wr = w >> 1, wc = w & 1;
    const int rg = blockIdx.x >> 7;       // 0..1
    const int cg = blockIdx.x & 127;
    const int lq = l >> 4, sp = l & 15;
    const int g0 = l & 3;

    // ---- stage W into LDS (once): 16 rounds x 8 waves = 128 segs of 1 KiB ----
    for (int r = 0; r < 16; ++r) {
        const int seg = w * 16 + r;
        const int bn = seg >> 2, q = seg & 3;
        const unsigned short* src =
            Wq + ((size_t)((bn & 3) * 1024 + cg * 8 + (bn >> 2))) * 2048 +
            (size_t)((q * 64 + l) ^ (bn & 7)) * 8;
        gll16(src, Wl + seg * 1024);
    }

    // ---- A staging invariants (2 gll/thread/chunk, 16 segs of 1 KiB) ----
    const int row0 = (w * 2 + 0) * 4 + (l >> 4);
    const int row1 = (w * 2 + 1) * 4 + (l >> 4);
    const unsigned sw0 = (unsigned)(((l & 15) ^ (row0 & 7)) * 8);
    const unsigned sw1 = (unsigned)(((l & 15) ^ (row1 & 7)) * 8);
    const unsigned short* xb0 = Xbf + (size_t)(rg * 64 + row0) * 1024 + sw0;
    const unsigned short* xb1 = Xbf + (size_t)(rg * 64 + row1) * 1024 + sw1;
    const unsigned short* hb0 = hbuf + (size_t)(rg * 64 + row0) * 1024 + sw0;
    const unsigned short* hb1 = hbuf + (size_t)(rg * 64 + row1) * 1024 + sw1;
    const unsigned adst0 = (unsigned)((w * 2 + 0) * 1024);
    const unsigned adst1 = (unsigned)((w * 2 + 1) * 1024);

    auto issueA = [&](int c, unsigned char* buf, int t) {
        if (c < 8) {
            const size_t o = (size_t)t * 131072 + c * 128;
            gll16(xb0 + o, buf + adst0);
            gll16(xb1 + o, buf + adst1);
        } else {
            const size_t o = (size_t)((t + 1) & 1) * 131072 + (c - 8) * 128;
            gll16(hb0 + o, buf + adst0);
            gll16(hb1 + o, buf + adst1);
        }
    };

    // ---- compute invariants ----
    const int arow = wr * 16 + sp;
    const unsigned abase = (unsigned)(arow * 256), axor = (unsigned)((arow & 7) << 4);
    const int bn = wc * 16 + sp;
    const unsigned bbase = (unsigned)(bn * 4096), bxor = (unsigned)((bn & 7) << 4);

    // epilogue mapping
    const int j0 = cg * 8 + wc * 4;          // first of this wave's 4 h-cols
    const int j = j0 + (sp >> 2);
    const int cidx = sp >> 2;                // column index within the 4-col group
    const int srcb = l & 48;                 // lq*16: transpose source lane base
    const float biasv = (g0 == 0) ? bfp[j] : (g0 == 1) ? bip[j]
                      : (g0 == 2) ? bgp[j] : bop[j];
    const int rbase = rg * 64 + wr * 16 + lq * 4;

    float c4[4] = {0.f, 0.f, 0.f, 0.f};

    issueA(0, Ab0, 0);  // first x chunk of t=0 (in flight during W stage drain)

    for (int t = 0; t < TT; ++t) {
        if (t > 0) {
            if (tid < 64) {  // wave 0 spins, relaxed agent loads
                const unsigned* p = cnt + (rg * 8 + (tid & 7)) * 64;
                const unsigned tgt = 16u * (unsigned)t;
                while (__hip_atomic_load(p, __ATOMIC_RELAXED,
                                         __HIP_MEMORY_SCOPE_AGENT) < tgt)
                    __builtin_amdgcn_s_sleep(2);
            }
            __syncthreads();  // joins spin; drains prefetched x chunk 0 gll
            // per-wave acquire: invalidate L1/L2 so h reads see remote stores
            __builtin_amdgcn_fence(__ATOMIC_ACQUIRE, "agent");
        } else {
            __syncthreads();  // t=0: drains W-stage + x chunk 0
        }

        const int nch = (t == 0) ? 8 : 16;
        f32x4 acc_a = {biasv, biasv, biasv, biasv};
        f32x4 acc_b = {0.f, 0.f, 0.f, 0.f};

        for (int c = 0; c < nch; ++c) {
            unsigned char* cur = (c & 1) ? Ab1 : Ab0;
            unsigned char* nxt = (c & 1) ? Ab0 : Ab1;
            if (c + 1 < nch) issueA(c + 1, nxt, t);
#pragma unroll
            for (int ks = 0; ks < 4; ++ks) {
                const unsigned as = abase + (((unsigned)((ks * 4 + lq) << 4)) ^ axor);
                const unsigned bs = bbase + (((unsigned)((c * 16 + ks * 4 + lq) << 4)) ^ bxor);
                short8 a = *(const short8*)(cur + as);
                short8 b = *(const short8*)(Wl + bs);
                if (ks & 1) acc_b = __builtin_amdgcn_mfma_f32_16x16x32_bf16(a, b, acc_b, 0, 0, 0);
                else        acc_a = __builtin_amdgcn_mfma_f32_16x16x32_bf16(a, b, acc_a, 0, 0, 0);
            }
            __syncthreads();
        }

        // ---- epilogue: gate combine (lanes g0==0 meaningful), c/h update ----
        unsigned short* hnx = hbuf + (size_t)(t & 1) * 131072;
        f32x4 z4 = acc_a + acc_b;
        float hh[4];
#pragma unroll
        for (int r = 0; r < 4; ++r) {
            float z = z4[r];
            float v1 = __shfl_xor(z, 1);
            float v2 = __shfl_xor(z, 2);
            float v3 = __shfl_xor(z, 3);
            float fg = sigmoidf_(z);
            float ig = sigmoidf_(v1);
            float gg = tanhf(v2);
            float og = sigmoidf_(v3);
            float cc = fg * c4[r] + ig * gg;
            c4[r] = cc;                      // garbage in g0!=0 lanes, never read
            hh[r] = og * tanhf(cc);
        }

        // 4x4 transpose among lanes srcb+{0,4,8,12}: lane cidx==r gets row
        // rbase+r's 4 cols -> float4 out store + 8B agent write-through h store
#pragma unroll
        for (int r = 0; r < 4; ++r) {
            float e0 = __shfl(hh[r], srcb + 0);
            float e1 = __shfl(hh[r], srcb + 4);
            float e2 = __shfl(hh[r], srcb + 8);
            float e3 = __shfl(hh[r], srcb + 12);
            if (g0 == 0 && cidx == r) {
                const int row = rbase + r;
                float4 o4; o4.x = e0; o4.y = e1; o4.z = e2; o4.w = e3;
                *(float4*)(&out[((size_t)t * BB + row) * 1024 + j0]) = o4;
                unsigned long long h8 =
                    (unsigned long long)((unsigned)f2bf(e0) | ((unsigned)f2bf(e1) << 16)) |
                    ((unsigned long long)((unsigned)f2bf(e2) | ((unsigned)f2bf(e3) << 16)) << 32);
                __hip_atomic_store((unsigned long long*)&hnx[(size_t)row * 1024 + j0],
                                   h8, __ATOMIC_RELAXED, __HIP_MEMORY_SCOPE_AGENT);
            }
            if (t == TT - 1) {
                float d0 = __shfl(c4[r], srcb + 0);
                float d1 = __shfl(c4[r], srcb + 4);
                float d2 = __shfl(c4[r], srcb + 8);
                float d3 = __shfl(c4[r], srcb + 12);
                if (g0 == 0 && cidx == r) {
                    const int row = rbase + r;
                    float4 o4; o4.x = e0; o4.y = e1; o4.z = e2; o4.w = e3;
                    float4 q4; q4.x = d0; q4.y = d1; q4.z = d2; q4.w = d3;
                    *(float4*)(&out[(size_t)TT * BB * 1024 + (size_t)row * 1024 + j0]) = o4;
                    *(float4*)(&out[(size_t)TT * BB * 1024 + (size_t)BB * 1024 +
                                    (size_t)row * 1024 + j0]) = q4;
                }
            }
        }

        if (t < TT - 1) {
            __syncthreads();  // vmcnt(0) drains each thread's h write-throughs
            if (tid == 0)
                __hip_atomic_fetch_add(cnt + (rg * 8 + (cg & 7)) * 64, 1u,
                                       __ATOMIC_RELEASE, __HIP_MEMORY_SCOPE_AGENT);
            issueA(0, Ab0, t + 1);  // next step's x chunk 0 hides under spin
        }
    }
}

// ================= fallback path (R2, proven) =================

__device__ __forceinline__ unsigned aoff(int row, int k) {
    return (unsigned)(row * 256 + ((k * 2) ^ ((row & 7) << 4)));
}

__global__ __launch_bounds__(256) void lstm_step(
    const float* __restrict__ X, const unsigned short* __restrict__ Wq,
    const float* __restrict__ bfp, const float* __restrict__ bip,
    const float* __restrict__ bgp, const float* __restrict__ bop,
    const unsigned short* __restrict__ h_prev, unsigned short* __restrict__ h_next,
    float* __restrict__ c_ws, float* __restrict__ out, int t) {
    __shared__ __align__(16) unsigned char smem[32768];
    const int tid = threadIdx.x;
    const int l = tid & 63;
    const int w = tid >> 6;
    const int wr = w >> 1, wc = w & 1;
    const int rg = blockIdx.x >> 7;
    const int cg = blockIdx.x & 127;
    const int lq = l >> 4;
    const int sp = l & 15;
    const int g0 = l & 3;
    const int j = cg * 8 + wc * 4 + (sp >> 2);
    const float biasv = (g0 == 0) ? bfp[j] : (g0 == 1) ? bip[j]
                      : (g0 == 2) ? bgp[j] : bop[j];
    f32x4 acc_a = {biasv, biasv, biasv, biasv};
    f32x4 acc_b = {0.f, 0.f, 0.f, 0.f};
    const int bn0 = w * 8 + lq, bn1 = bn0 + 4;
    const unsigned short* wsrc0 =
        Wq + ((size_t)((bn0 & 3) * 1024 + cg * 8 + (bn0 >> 2))) * 2048 + (sp ^ (bn0 & 7)) * 8;
    const unsigned short* wsrc1 =
        Wq + ((size_t)((bn1 & 3) * 1024 + cg * 8 + (bn1 >> 2))) * 2048 + (sp ^ (bn1 & 7)) * 8;
    const unsigned short* hsrc0 = h_prev + (size_t)(rg * 32 + bn0) * 1024 + (sp ^ (bn0 & 7)) * 8;
    const unsigned short* hsrc1 = h_prev + (size_t)(rg * 32 + bn1) * 1024 + (sp ^ (bn1 & 7)) * 8;
    const int xrow = tid >> 3;
    const int xs = (tid & 7) * 2;
    const float* xsrc = X + ((size_t)t * BB + rg * 32 + xrow) * 1024 + xs * 8;
    const unsigned xw0 = (unsigned)(xrow * 256 + ((xs * 16) ^ ((xrow & 7) << 4)));
    const unsigned xw1 = (unsigned)(xrow * 256 + (((xs + 1) * 16) ^ ((xrow & 7) << 4)));
    float4 xv0, xv1, xv2, xv3;
    auto load_x = [&](int c) {
        const float* p = xsrc + c * 128;
        xv0 = *(const float4*)(p); xv1 = *(const float4*)(p + 4);
        xv2 = *(const float4*)(p + 8); xv3 = *(const float4*)(p + 12);
    };
    auto write_x = [&](int buf) {
        unsigned char* Ab = smem + (buf ? 8192 : 0);
        uint4 u0, u1;
        u0.x = (unsigned)f2bf(xv0.x) | ((unsigned)f2bf(xv0.y) << 16);
        u0.y = (unsigned)f2bf(xv0.z) | ((unsigned)f2bf(xv0.w) << 16);
        u0.z = (unsigned)f2bf(xv1.x) | ((unsigned)f2bf(xv1.y) << 16);
        u0.w = (unsigned)f2bf(xv1.z) | ((unsigned)f2bf(xv1.w) << 16);
        u1.x = (unsigned)f2bf(xv2.x) | ((unsigned)f2bf(xv2.y) << 16);
        u1.y = (unsigned)f2bf(xv2.z) | ((unsigned)f2bf(xv2.w) << 16);
        u1.z = (unsigned)f2bf(xv3.x) | ((unsigned)f2bf(xv3.y) << 16);
        u1.w = (unsigned)f2bf(xv3.z) | ((unsigned)f2bf(xv3.w) << 16);
        *(uint4*)(Ab + xw0) = u0; *(uint4*)(Ab + xw1) = u1;
    };
    auto stage_B = [&](int c, int buf) {
        unsigned char* Bb = smem + 16384 + (buf ? 8192 : 0);
        gll16(wsrc0 + c * 128, Bb + (w * 8) * 256);
        gll16(wsrc1 + c * 128, Bb + (w * 8 + 4) * 256);
    };
    auto stage_Ah = [&](int c, int buf) {
        unsigned char* Ab = smem + (buf ? 8192 : 0);
        gll16(hsrc0 + c * 128 - 1024, Ab + (w * 8) * 256);
        gll16(hsrc1 + c * 128 - 1024, Ab + (w * 8 + 4) * 256);
    };
    auto compute = [&](int buf) {
        const unsigned char* Ab = smem + (buf ? 8192 : 0);
        const unsigned char* Bb = smem + 16384 + (buf ? 8192 : 0);
        const int ar = wr * 16 + sp;
        const int br = wc * 16 + sp;
#pragma unroll
        for (int ks = 0; ks < 4; ++ks) {
            const int kk = ks * 32 + lq * 8;
            short8 a = *(const short8*)(Ab + aoff(ar, kk));
            short8 b = *(const short8*)(Bb + aoff(br, kk));
            if (ks & 1) acc_b = __builtin_amdgcn_mfma_f32_16x16x32_bf16(a, b, acc_b, 0, 0, 0);
            else        acc_a = __builtin_amdgcn_mfma_f32_16x16x32_bf16(a, b, acc_a, 0, 0, 0);
        }
    };
    load_x(0); stage_B(0, 0); write_x(0);
    __syncthreads();
    for (int c = 0; c < 16; ++c) {
        const int buf = c & 1, nbuf = buf ^ 1;
        const int nx = c + 1;
        if (c < 15) {
            if (nx < 8) load_x(nx);
            stage_B(nx, nbuf);
            if (nx >= 8) stage_Ah(nx, nbuf);
        }
        compute(buf);
        if (c < 15 && nx < 8) write_x(nbuf);
        __syncthreads();
    }
    f32x4 z4 = acc_a + acc_b;
    const int rbase = rg * 32 + wr * 16 + lq * 4;
#pragma unroll
    for (int r = 0; r < 4; ++r) {
        float z = z4[r];
        float v1 = __shfl_xor(z, 1);
        float v2 = __shfl_xor(z, 2);
        float v3 = __shfl_xor(z, 3);
        if (g0 == 0) {
            float fg = sigmoidf_(z), ig = sigmoidf_(v1);
            float gg = tanhf(v2), og = sigmoidf_(v3);
            const int row = rbase + r;
            const size_t idx = (size_t)row * 1024 + j;
            float cc = fg * c_ws[idx] + ig * gg;
            c_ws[idx] = cc;
            float hh = og * tanhf(cc);
            out[((size_t)t * BB + row) * 1024 + j] = hh;
            h_next[idx] = f2bf(hh);
            if (t == TT - 1) {
                out[(size_t)TT * BB * 1024 + idx] = hh;
                out[(size_t)TT * BB * 1024 + (size_t)BB * 1024 + idx] = cc;
            }
        }
    }
}

// ---------------- host ----------------

extern "C" void kernel_launch(void* const* d_in, const int* in_sizes, int n_in,
                              void* d_out, int out_size, void* d_ws, size_t ws_size,
                              hipStream_t stream) {
    const float* X  = (const float*)d_in[0];
    const float* Wf = (const float*)d_in[1];
    const float* bf = (const float*)d_in[2];
    const float* Wi = (const float*)d_in[3];
    const float* bi = (const float*)d_in[4];
    const float* Wg = (const float*)d_in[5];
    const float* bg = (const float*)d_in[6];
    const float* Wo = (const float*)d_in[7];
    const float* bo = (const float*)d_in[8];
    unsigned char* ws = (unsigned char*)d_ws;

    if (ws_size >= WS_NEED) {
        unsigned short* Wq = (unsigned short*)ws;
        unsigned short* Xb = (unsigned short*)(ws + XBF_OFF);
        unsigned short* hb = (unsigned short*)(ws + HBUF_OFF);
        unsigned* cnt = (unsigned*)(ws + CNT_OFF);
        float* outp = (float*)d_out;

        cvt_w<<<dim3(8192), dim3(256), 0, stream>>>(Wf, Wi, Wg, Wo, Wq);
        cvt_x<<<dim3(32768), dim3(256), 0, stream>>>(X, Xb);
        hipMemsetAsync(cnt, 0, 4096, stream);
        hipFuncSetAttribute((const void*)lstm_persist,
                            hipFuncAttributeMaxDynamicSharedMemorySize, 163840);

        const unsigned short* XbC = Xb;
        const unsigned short* WqC = Wq;
        void* args[] = {(void*)&XbC, (void*)&WqC, (void*)&bf, (void*)&bi,
                        (void*)&bg, (void*)&bo, (void*)&hb, (void*)&cnt, (void*)&outp};
        hipLaunchCooperativeKernel((const void*)lstm_persist, dim3(256), dim3(512),
                                   args, 163840, stream);
    } else {
        unsigned short* Wq = (unsigned short*)ws;
        unsigned short* hbuf = (unsigned short*)(ws + 16777216);
        float* c_ws = (float*)(ws + 16777216 + 524288);
        cvt_w<<<dim3(8192), dim3(256), 0, stream>>>(Wf, Wi, Wg, Wo, Wq);
        zero_ws<<<dim3(1024), dim3(256), 0, stream>>>((unsigned int*)(ws + 16777216));
        for (int t = 0; t < TT; ++t) {
            const unsigned short* hp = hbuf + (size_t)(t & 1) * (BB * 1024);
            unsigned short* hn = hbuf + (size_t)((t + 1) & 1) * (BB * 1024);
            lstm_step<<<dim3(512), dim3(256), 0, stream>>>(
                X, Wq, bf, bi, bg, bo, hp, hn, c_ws, (float*)d_out, t);
        }
    }
}

// Round 6
// 7385.255 us; speedup vs baseline: 5.8067x; 2.1447x over previous
//
#include <hip/hip_runtime.h>

// LSTM T=512,B=128,D=H=1024. R6: Zx = X·Wx^T precomputed in parallel chunks
// (no time dependency), per-step kernels do only the h-GEMM (K=1024).
// Weights pre-interleaved to gate-col order n = hcol*4+gate, [4096][1024] bf16.
// Step kernel: 512 blocks (4 rg x 128 cg), 256 thr, tile 32 rows x 32 n-cols,
// 8 K-chunks double-buffered, gll(16B) staging with pre-swizzled source.
// Epilogue: R5-proven 4x4 shuffle transpose -> float4 out, uint2 h, float4 c.

#define TT 512
#define BB 128

typedef __attribute__((ext_vector_type(8))) short short8;
typedef __attribute__((ext_vector_type(4))) float f32x4;

// ws layout
#define WX_OFF 0u                    // [4096][1024] bf16 = 8 MiB
#define WH_OFF 8388608u              // [4096][1024] bf16 = 8 MiB
#define H_OFF  16777216u             // 2 x [128][1024] bf16 = 512 KiB
#define C_OFF  17301504u             // [128][1024] f32 = 512 KiB
#define ZX_OFF 17825792u             // [C][128][4096] f32, C adaptive

__device__ __forceinline__ unsigned short f2bf(float x) {
    union { float f; unsigned int u; } a; a.f = x;
    unsigned int r = a.u + 0x7fff + ((a.u >> 16) & 1);
    return (unsigned short)(r >> 16);
}

__device__ __forceinline__ float sigmoidf_(float x) {
    return 1.0f / (1.0f + expf(-x));
}

__device__ __forceinline__ void gll16(const void* g, void* l) {
    __builtin_amdgcn_global_load_lds(
        (const __attribute__((address_space(1))) unsigned int*)g,
        (__attribute__((address_space(3))) unsigned int*)l, 16, 0, 0);
}

// ---------------- phase 0: interleave+convert weights, zero state ----------------

__global__ __launch_bounds__(256) void cvt_wi(const float* __restrict__ Wf,
                                              const float* __restrict__ Wi,
                                              const float* __restrict__ Wg,
                                              const float* __restrict__ Wo,
                                              unsigned short* __restrict__ Wxi,
                                              unsigned short* __restrict__ Whi) {
    const int n = blockIdx.x;              // 0..4095: gate-col, n = hcol*4+gate
    const int k8 = threadIdx.x * 8;        // 0..2040
    const int gate = n & 3, hcol = n >> 2;
    const float* src = ((gate == 0) ? Wf : (gate == 1) ? Wi : (gate == 2) ? Wg : Wo)
                       + (size_t)hcol * 2048 + k8;
    float4 a = *(const float4*)src;
    float4 b = *(const float4*)(src + 4);
    uint4 u;
    u.x = (unsigned)f2bf(a.x) | ((unsigned)f2bf(a.y) << 16);
    u.y = (unsigned)f2bf(a.z) | ((unsigned)f2bf(a.w) << 16);
    u.z = (unsigned)f2bf(b.x) | ((unsigned)f2bf(b.y) << 16);
    u.w = (unsigned)f2bf(b.z) | ((unsigned)f2bf(b.w) << 16);
    unsigned short* dst = (k8 < 1024) ? Wxi + (size_t)n * 1024 + k8
                                      : Whi + (size_t)n * 1024 + (k8 - 1024);
    *(uint4*)dst = u;
}

__global__ __launch_bounds__(256) void zero_ws(unsigned int* __restrict__ p) {
    p[blockIdx.x * 256 + threadIdx.x] = 0u;  // grid sized exactly (1 MiB)
}

// ---------------- Zx GEMM: [C*128 x 4096 x 1024], fully parallel ----------------
// grid = C*4*128 blocks: mt = bid>>7 (32 M-rows), cg = bid&127 (32 n-cols)

__global__ __launch_bounds__(256) void gemm_zx(
    const float* __restrict__ X,            // chunk base: [C*128][1024] f32
    const unsigned short* __restrict__ Wxi, // [4096][1024] bf16
    float* __restrict__ Zx) {               // [C*128][4096] f32
    __shared__ __align__(16) unsigned char smem[32768];
    // A bufs 0/8192 (32 rows x 128 k bf16, 256 B rows, XOR-swizzled)
    // B bufs 16384/24576

    const int tid = threadIdx.x;
    const int l = tid & 63;
    const int w = tid >> 6;
    const int wr = w >> 1, wc = w & 1;
    const int mt = blockIdx.x >> 7;
    const int cg = blockIdx.x & 127;
    const int lq = l >> 4, sp = l & 15;

    f32x4 acc_a = {0.f, 0.f, 0.f, 0.f};
    f32x4 acc_b = {0.f, 0.f, 0.f, 0.f};

    // A: X fp32 reg-stage (R2-proven mapping)
    const int xrow = tid >> 3;
    const int xs = (tid & 7) * 2;
    const float* xsrc = X + (size_t)(mt * 32 + xrow) * 1024 + xs * 8;
    const unsigned xw0 = (unsigned)(xrow * 256 + ((xs * 16) ^ ((xrow & 7) << 4)));
    const unsigned xw1 = (unsigned)(xrow * 256 + (((xs + 1) * 16) ^ ((xrow & 7) << 4)));
    float4 xv0, xv1, xv2, xv3;

    // B: Wxi gll with pre-swizzled source (R2-proven mapping)
    const int bn0 = w * 8 + lq, bn1 = bn0 + 4;
    const unsigned short* wsrc0 = Wxi + (size_t)(cg * 32 + bn0) * 1024 + (sp ^ (bn0 & 7)) * 8;
    const unsigned short* wsrc1 = Wxi + (size_t)(cg * 32 + bn1) * 1024 + (sp ^ (bn1 & 7)) * 8;

    auto load_x = [&](int c) {
        const float* p = xsrc + c * 128;
        xv0 = *(const float4*)(p);     xv1 = *(const float4*)(p + 4);
        xv2 = *(const float4*)(p + 8); xv3 = *(const float4*)(p + 12);
    };
    auto write_x = [&](int buf) {
        unsigned char* Ab = smem + (buf ? 8192 : 0);
        uint4 u0, u1;
        u0.x = (unsigned)f2bf(xv0.x) | ((unsigned)f2bf(xv0.y) << 16);
        u0.y = (unsigned)f2bf(xv0.z) | ((unsigned)f2bf(xv0.w) << 16);
        u0.z = (unsigned)f2bf(xv1.x) | ((unsigned)f2bf(xv1.y) << 16);
        u0.w = (unsigned)f2bf(xv1.z) | ((unsigned)f2bf(xv1.w) << 16);
        u1.x = (unsigned)f2bf(xv2.x) | ((unsigned)f2bf(xv2.y) << 16);
        u1.y = (unsigned)f2bf(xv2.z) | ((unsigned)f2bf(xv2.w) << 16);
        u1.z = (unsigned)f2bf(xv3.x) | ((unsigned)f2bf(xv3.y) << 16);
        u1.w = (unsigned)f2bf(xv3.z) | ((unsigned)f2bf(xv3.w) << 16);
        *(uint4*)(Ab + xw0) = u0; *(uint4*)(Ab + xw1) = u1;
    };
    auto stage_B = [&](int c, int buf) {
        unsigned char* Bb = smem + 16384 + (buf ? 8192 : 0);
        gll16(wsrc0 + c * 128, Bb + (w * 8) * 256);
        gll16(wsrc1 + c * 128, Bb + (w * 8 + 4) * 256);
    };
    auto compute = [&](int buf) {
        const unsigned char* Ab = smem + (buf ? 8192 : 0);
        const unsigned char* Bb = smem + 16384 + (buf ? 8192 : 0);
        const int ar = wr * 16 + sp;
        const int br = wc * 16 + sp;
        const unsigned abase = (unsigned)(ar * 256), axor = (unsigned)((ar & 7) << 4);
        const unsigned bbase = (unsigned)(br * 256), bxor = (unsigned)((br & 7) << 4);
#pragma unroll
        for (int ks = 0; ks < 4; ++ks) {
            const unsigned kk2 = (unsigned)((ks * 4 + lq) << 4);
            short8 a = *(const short8*)(Ab + abase + (kk2 ^ axor));
            short8 b = *(const short8*)(Bb + bbase + (kk2 ^ bxor));
            if (ks & 1) acc_b = __builtin_amdgcn_mfma_f32_16x16x32_bf16(a, b, acc_b, 0, 0, 0);
            else        acc_a = __builtin_amdgcn_mfma_f32_16x16x32_bf16(a, b, acc_a, 0, 0, 0);
        }
    };

    load_x(0); stage_B(0, 0); write_x(0);
    __syncthreads();
    for (int c = 0; c < 8; ++c) {
        const int buf = c & 1, nbuf = buf ^ 1;
        if (c < 7) { load_x(c + 1); stage_B(c + 1, nbuf); }
        compute(buf);
        if (c < 7) write_x(nbuf);
        __syncthreads();
    }

    // epilogue: scalar stores, coalesced per quarter-wave
    const int rowb = mt * 32 + wr * 16 + lq * 4;
    const int n = cg * 32 + wc * 16 + sp;
    f32x4 z4 = acc_a + acc_b;
#pragma unroll
    for (int r = 0; r < 4; ++r)
        Zx[(size_t)(rowb + r) * 4096 + n] = z4[r];
}

// ---------------- per-timestep h-GEMM + gate epilogue ----------------
// grid = 512: rg = bid>>7 (32 batch rows), cg = bid&127 (32 n-cols)

__global__ __launch_bounds__(256) void lstm_step2(
    const float* __restrict__ Zxt,           // [128][4096] f32, this step
    const unsigned short* __restrict__ Whi,  // [4096][1024] bf16
    const float* __restrict__ bfp, const float* __restrict__ bip,
    const float* __restrict__ bgp, const float* __restrict__ bop,
    const unsigned short* __restrict__ h_prev,  // [128][1024] bf16
    unsigned short* __restrict__ h_next,        // [128][1024] bf16
    float* __restrict__ c_ws,                   // [128][1024] f32
    float* __restrict__ out, int t) {
    __shared__ __align__(16) unsigned char smem[32768];

    const int tid = threadIdx.x;
    const int l = tid & 63;
    const int w = tid >> 6;
    const int wr = w >> 1, wc = w & 1;
    const int rg = blockIdx.x >> 7;
    const int cg = blockIdx.x & 127;
    const int lq = l >> 4, sp = l & 15;
    const int g0 = l & 3;
    const int n = cg * 32 + wc * 16 + sp;
    const int j = n >> 2;
    const int j0 = cg * 8 + wc * 4;
    const int cidx = sp >> 2;
    const int srcb = l & 48;
    const int rbase = rg * 32 + wr * 16 + lq * 4;

    // early independent loads: Zx (4), bias, c_prev (4) — hidden under GEMM
    const float biasv = (g0 == 0) ? bfp[j] : (g0 == 1) ? bip[j]
                      : (g0 == 2) ? bgp[j] : bop[j];
    float zx0 = Zxt[(size_t)(rbase + 0) * 4096 + n];
    float zx1 = Zxt[(size_t)(rbase + 1) * 4096 + n];
    float zx2 = Zxt[(size_t)(rbase + 2) * 4096 + n];
    float zx3 = Zxt[(size_t)(rbase + 3) * 4096 + n];
    float cp0 = c_ws[(size_t)(rbase + 0) * 1024 + j];
    float cp1 = c_ws[(size_t)(rbase + 1) * 1024 + j];
    float cp2 = c_ws[(size_t)(rbase + 2) * 1024 + j];
    float cp3 = c_ws[(size_t)(rbase + 3) * 1024 + j];

    f32x4 acc_a = {0.f, 0.f, 0.f, 0.f};
    f32x4 acc_b = {0.f, 0.f, 0.f, 0.f};

    // A: h rows via gll, pre-swizzled source; B: Whi rows likewise
    const int bn0 = w * 8 + lq, bn1 = bn0 + 4;
    const unsigned short* hsrc0 = h_prev + (size_t)(rg * 32 + bn0) * 1024 + (sp ^ (bn0 & 7)) * 8;
    const unsigned short* hsrc1 = h_prev + (size_t)(rg * 32 + bn1) * 1024 + (sp ^ (bn1 & 7)) * 8;
    const unsigned short* wsrc0 = Whi + (size_t)(cg * 32 + bn0) * 1024 + (sp ^ (bn0 & 7)) * 8;
    const unsigned short* wsrc1 = Whi + (size_t)(cg * 32 + bn1) * 1024 + (sp ^ (bn1 & 7)) * 8;

    auto stage_A = [&](int c, int buf) {
        unsigned char* Ab = smem + (buf ? 8192 : 0);
        gll16(hsrc0 + c * 128, Ab + (w * 8) * 256);
        gll16(hsrc1 + c * 128, Ab + (w * 8 + 4) * 256);
    };
    auto stage_B = [&](int c, int buf) {
        unsigned char* Bb = smem + 16384 + (buf ? 8192 : 0);
        gll16(wsrc0 + c * 128, Bb + (w * 8) * 256);
        gll16(wsrc1 + c * 128, Bb + (w * 8 + 4) * 256);
    };
    auto compute = [&](int buf) {
        const unsigned char* Ab = smem + (buf ? 8192 : 0);
        const unsigned char* Bb = smem + 16384 + (buf ? 8192 : 0);
        const int ar = wr * 16 + sp;
        const int br = wc * 16 + sp;
        const unsigned abase = (unsigned)(ar * 256), axor = (unsigned)((ar & 7) << 4);
        const unsigned bbase = (unsigned)(br * 256), bxor = (unsigned)((br & 7) << 4);
#pragma unroll
        for (int ks = 0; ks < 4; ++ks) {
            const unsigned kk2 = (unsigned)((ks * 4 + lq) << 4);
            short8 a = *(const short8*)(Ab + abase + (kk2 ^ axor));
            short8 b = *(const short8*)(Bb + bbase + (kk2 ^ bxor));
            if (ks & 1) acc_b = __builtin_amdgcn_mfma_f32_16x16x32_bf16(a, b, acc_b, 0, 0, 0);
            else        acc_a = __builtin_amdgcn_mfma_f32_16x16x32_bf16(a, b, acc_a, 0, 0, 0);
        }
    };

    stage_A(0, 0); stage_B(0, 0);
    __syncthreads();
    for (int c = 0; c < 8; ++c) {
        const int buf = c & 1, nbuf = buf ^ 1;
        if (c < 7) { stage_A(c + 1, nbuf); stage_B(c + 1, nbuf); }
        compute(buf);
        __syncthreads();
    }

    // epilogue: z = zh + zx + bias; gates via lane-xor; 4x4 transpose stores
    f32x4 z4 = acc_a + acc_b;
    z4[0] += zx0 + biasv; z4[1] += zx1 + biasv;
    z4[2] += zx2 + biasv; z4[3] += zx3 + biasv;
    float cpv[4] = {cp0, cp1, cp2, cp3};
    float hhv[4], ccv[4];
#pragma unroll
    for (int r = 0; r < 4; ++r) {
        float z = z4[r];
        float v1 = __shfl_xor(z, 1);
        float v2 = __shfl_xor(z, 2);
        float v3 = __shfl_xor(z, 3);
        float fg = sigmoidf_(z);    // meaningful in g0==0 lanes
        float ig = sigmoidf_(v1);
        float gg = tanhf(v2);
        float og = sigmoidf_(v3);
        float cc = fg * cpv[r] + ig * gg;
        ccv[r] = cc;
        hhv[r] = og * tanhf(cc);
    }
#pragma unroll
    for (int r = 0; r < 4; ++r) {
        float e0 = __shfl(hhv[r], srcb + 0);
        float e1 = __shfl(hhv[r], srcb + 4);
        float e2 = __shfl(hhv[r], srcb + 8);
        float e3 = __shfl(hhv[r], srcb + 12);
        float d0 = __shfl(ccv[r], srcb + 0);
        float d1 = __shfl(ccv[r], srcb + 4);
        float d2 = __shfl(ccv[r], srcb + 8);
        float d3 = __shfl(ccv[r], srcb + 12);
        if (g0 == 0 && cidx == r) {
            const int row = rbase + r;
            float4 o4; o4.x = e0; o4.y = e1; o4.z = e2; o4.w = e3;
            float4 q4; q4.x = d0; q4.y = d1; q4.z = d2; q4.w = d3;
            *(float4*)(&out[((size_t)t * BB + row) * 1024 + j0]) = o4;
            *(float4*)(&c_ws[(size_t)row * 1024 + j0]) = q4;
            uint2 h2;
            h2.x = (unsigned)f2bf(e0) | ((unsigned)f2bf(e1) << 16);
            h2.y = (unsigned)f2bf(e2) | ((unsigned)f2bf(e3) << 16);
            *(uint2*)(&h_next[(size_t)row * 1024 + j0]) = h2;
            if (t == TT - 1) {
                *(float4*)(&out[(size_t)TT * BB * 1024 + (size_t)row * 1024 + j0]) = o4;
                *(float4*)(&out[(size_t)TT * BB * 1024 + (size_t)BB * 1024 +
                                (size_t)row * 1024 + j0]) = q4;
            }
        }
    }
}

// ---------------- host ----------------

extern "C" void kernel_launch(void* const* d_in, const int* in_sizes, int n_in,
                              void* d_out, int out_size, void* d_ws, size_t ws_size,
                              hipStream_t stream) {
    const float* X  = (const float*)d_in[0];
    const float* Wf = (const float*)d_in[1];
    const float* bf = (const float*)d_in[2];
    const float* Wi = (const float*)d_in[3];
    const float* bi = (const float*)d_in[4];
    const float* Wg = (const float*)d_in[5];
    const float* bg = (const float*)d_in[6];
    const float* Wo = (const float*)d_in[7];
    const float* bo = (const float*)d_in[8];
    unsigned char* ws = (unsigned char*)d_ws;

    unsigned short* Wxi = (unsigned short*)(ws + WX_OFF);
    unsigned short* Whi = (unsigned short*)(ws + WH_OFF);
    unsigned short* hbuf = (unsigned short*)(ws + H_OFF);
    float* c_ws = (float*)(ws + C_OFF);
    float* Zx = (float*)(ws + ZX_OFF);
    float* outp = (float*)d_out;

    // adaptive Zx chunk length (deterministic in ws_size)
    int C = 4;
    const int cands[8] = {512, 256, 128, 64, 32, 16, 8, 4};
    for (int i = 0; i < 8; ++i) {
        if ((size_t)ZX_OFF + (size_t)cands[i] * 2097152u <= ws_size) { C = cands[i]; break; }
    }

    cvt_wi<<<dim3(4096), dim3(256), 0, stream>>>(Wf, Wi, Wg, Wo, Wxi, Whi);
    zero_ws<<<dim3(1024), dim3(256), 0, stream>>>((unsigned int*)(ws + H_OFF));

    const int nchunks = TT / C;
    for (int ch = 0; ch < nchunks; ++ch) {
        gemm_zx<<<dim3(C * 4 * 128), dim3(256), 0, stream>>>(
            X + (size_t)ch * C * BB * 1024, Wxi, Zx);
        for (int tl = 0; tl < C; ++tl) {
            const int t = ch * C + tl;
            const unsigned short* hp = hbuf + (size_t)(t & 1) * (BB * 1024);
            unsigned short* hn = hbuf + (size_t)((t + 1) & 1) * (BB * 1024);
            lstm_step2<<<dim3(512), dim3(256), 0, stream>>>(
                Zx + (size_t)tl * BB * 4096, Whi, bf, bi, bg, bo,
                hp, hn, c_ws, outp, t);
        }
    }
}

// Round 7
// 6826.129 us; speedup vs baseline: 6.2823x; 1.0819x over previous
//
#include <hip/hip_runtime.h>

// LSTM T=512,B=128,D=H=1024. R7: R6 structure (Zx precompute + per-step h-GEMM)
// with counted-vmcnt deep pipeline in the step kernel: 4 LDS buffers, 3 chunks
// in flight, raw s_barrier + s_waitcnt vmcnt(8) (never 0 until tail).
// Weights pre-interleaved to gate-col order n = hcol*4+gate, [4096][1024] bf16.
// Epilogue: 4x4 shuffle transpose -> float4 out, uint2 h, float4 c; fast
// __expf-based sigmoid/tanh.

#define TT 512
#define BB 128

typedef __attribute__((ext_vector_type(8))) short short8;
typedef __attribute__((ext_vector_type(4))) float f32x4;

// ws layout
#define WX_OFF 0u                    // [4096][1024] bf16 = 8 MiB
#define WH_OFF 8388608u              // [4096][1024] bf16 = 8 MiB
#define H_OFF  16777216u             // 2 x [128][1024] bf16 = 512 KiB
#define C_OFF  17301504u             // [128][1024] f32 = 512 KiB
#define ZX_OFF 17825792u             // [C][128][4096] f32, C adaptive

__device__ __forceinline__ unsigned short f2bf(float x) {
    union { float f; unsigned int u; } a; a.f = x;
    unsigned int r = a.u + 0x7fff + ((a.u >> 16) & 1);
    return (unsigned short)(r >> 16);
}

__device__ __forceinline__ float fsig(float x) {
    float e = __expf(-x);
    return __builtin_amdgcn_rcpf(1.0f + e);   // |x| large handled: e->0 or inf
}
__device__ __forceinline__ float ftanh(float x) {
    float e = __expf(2.0f * x);
    return 1.0f - 2.0f * __builtin_amdgcn_rcpf(e + 1.0f);
}
__device__ __forceinline__ float sigmoidf_(float x) {
    return 1.0f / (1.0f + expf(-x));
}

__device__ __forceinline__ void gll16(const void* g, void* l) {
    __builtin_amdgcn_global_load_lds(
        (const __attribute__((address_space(1))) unsigned int*)g,
        (__attribute__((address_space(3))) unsigned int*)l, 16, 0, 0);
}

// ---------------- phase 0: interleave+convert weights, zero state ----------------

__global__ __launch_bounds__(256) void cvt_wi(const float* __restrict__ Wf,
                                              const float* __restrict__ Wi,
                                              const float* __restrict__ Wg,
                                              const float* __restrict__ Wo,
                                              unsigned short* __restrict__ Wxi,
                                              unsigned short* __restrict__ Whi) {
    const int n = blockIdx.x;              // 0..4095: gate-col, n = hcol*4+gate
    const int k8 = threadIdx.x * 8;        // 0..2040
    const int gate = n & 3, hcol = n >> 2;
    const float* src = ((gate == 0) ? Wf : (gate == 1) ? Wi : (gate == 2) ? Wg : Wo)
                       + (size_t)hcol * 2048 + k8;
    float4 a = *(const float4*)src;
    float4 b = *(const float4*)(src + 4);
    uint4 u;
    u.x = (unsigned)f2bf(a.x) | ((unsigned)f2bf(a.y) << 16);
    u.y = (unsigned)f2bf(a.z) | ((unsigned)f2bf(a.w) << 16);
    u.z = (unsigned)f2bf(b.x) | ((unsigned)f2bf(b.y) << 16);
    u.w = (unsigned)f2bf(b.z) | ((unsigned)f2bf(b.w) << 16);
    unsigned short* dst = (k8 < 1024) ? Wxi + (size_t)n * 1024 + k8
                                      : Whi + (size_t)n * 1024 + (k8 - 1024);
    *(uint4*)dst = u;
}

__global__ __launch_bounds__(256) void zero_ws(unsigned int* __restrict__ p) {
    p[blockIdx.x * 256 + threadIdx.x] = 0u;  // grid sized exactly (1 MiB)
}

// ---------------- Zx GEMM: [C*128 x 4096 x 1024], fully parallel ----------------

__global__ __launch_bounds__(256) void gemm_zx(
    const float* __restrict__ X,            // chunk base: [C*128][1024] f32
    const unsigned short* __restrict__ Wxi, // [4096][1024] bf16
    float* __restrict__ Zx) {               // [C*128][4096] f32
    __shared__ __align__(16) unsigned char smem[32768];

    const int tid = threadIdx.x;
    const int l = tid & 63;
    const int w = tid >> 6;
    const int wr = w >> 1, wc = w & 1;
    const int mt = blockIdx.x >> 7;
    const int cg = blockIdx.x & 127;
    const int lq = l >> 4, sp = l & 15;

    f32x4 acc_a = {0.f, 0.f, 0.f, 0.f};
    f32x4 acc_b = {0.f, 0.f, 0.f, 0.f};

    const int xrow = tid >> 3;
    const int xs = (tid & 7) * 2;
    const float* xsrc = X + (size_t)(mt * 32 + xrow) * 1024 + xs * 8;
    const unsigned xw0 = (unsigned)(xrow * 256 + ((xs * 16) ^ ((xrow & 7) << 4)));
    const unsigned xw1 = (unsigned)(xrow * 256 + (((xs + 1) * 16) ^ ((xrow & 7) << 4)));
    float4 xv0, xv1, xv2, xv3;

    const int bn0 = w * 8 + lq, bn1 = bn0 + 4;
    const unsigned short* wsrc0 = Wxi + (size_t)(cg * 32 + bn0) * 1024 + (sp ^ (bn0 & 7)) * 8;
    const unsigned short* wsrc1 = Wxi + (size_t)(cg * 32 + bn1) * 1024 + (sp ^ (bn1 & 7)) * 8;

    auto load_x = [&](int c) {
        const float* p = xsrc + c * 128;
        xv0 = *(const float4*)(p);     xv1 = *(const float4*)(p + 4);
        xv2 = *(const float4*)(p + 8); xv3 = *(const float4*)(p + 12);
    };
    auto write_x = [&](int buf) {
        unsigned char* Ab = smem + (buf ? 8192 : 0);
        uint4 u0, u1;
        u0.x = (unsigned)f2bf(xv0.x) | ((unsigned)f2bf(xv0.y) << 16);
        u0.y = (unsigned)f2bf(xv0.z) | ((unsigned)f2bf(xv0.w) << 16);
        u0.z = (unsigned)f2bf(xv1.x) | ((unsigned)f2bf(xv1.y) << 16);
        u0.w = (unsigned)f2bf(xv1.z) | ((unsigned)f2bf(xv1.w) << 16);
        u1.x = (unsigned)f2bf(xv2.x) | ((unsigned)f2bf(xv2.y) << 16);
        u1.y = (unsigned)f2bf(xv2.z) | ((unsigned)f2bf(xv2.w) << 16);
        u1.z = (unsigned)f2bf(xv3.x) | ((unsigned)f2bf(xv3.y) << 16);
        u1.w = (unsigned)f2bf(xv3.z) | ((unsigned)f2bf(xv3.w) << 16);
        *(uint4*)(Ab + xw0) = u0; *(uint4*)(Ab + xw1) = u1;
    };
    auto stage_B = [&](int c, int buf) {
        unsigned char* Bb = smem + 16384 + (buf ? 8192 : 0);
        gll16(wsrc0 + c * 128, Bb + (w * 8) * 256);
        gll16(wsrc1 + c * 128, Bb + (w * 8 + 4) * 256);
    };
    auto compute = [&](int buf) {
        const unsigned char* Ab = smem + (buf ? 8192 : 0);
        const unsigned char* Bb = smem + 16384 + (buf ? 8192 : 0);
        const int ar = wr * 16 + sp;
        const int br = wc * 16 + sp;
        const unsigned abase = (unsigned)(ar * 256), axor = (unsigned)((ar & 7) << 4);
        const unsigned bbase = (unsigned)(br * 256), bxor = (unsigned)((br & 7) << 4);
#pragma unroll
        for (int ks = 0; ks < 4; ++ks) {
            const unsigned kk2 = (unsigned)((ks * 4 + lq) << 4);
            short8 a = *(const short8*)(Ab + abase + (kk2 ^ axor));
            short8 b = *(const short8*)(Bb + bbase + (kk2 ^ bxor));
            if (ks & 1) acc_b = __builtin_amdgcn_mfma_f32_16x16x32_bf16(a, b, acc_b, 0, 0, 0);
            else        acc_a = __builtin_amdgcn_mfma_f32_16x16x32_bf16(a, b, acc_a, 0, 0, 0);
        }
    };

    load_x(0); stage_B(0, 0); write_x(0);
    __syncthreads();
    for (int c = 0; c < 8; ++c) {
        const int buf = c & 1, nbuf = buf ^ 1;
        if (c < 7) { load_x(c + 1); stage_B(c + 1, nbuf); }
        compute(buf);
        if (c < 7) write_x(nbuf);
        __syncthreads();
    }

    const int rowb = mt * 32 + wr * 16 + lq * 4;
    const int n = cg * 32 + wc * 16 + sp;
    f32x4 z4 = acc_a + acc_b;
#pragma unroll
    for (int r = 0; r < 4; ++r)
        Zx[(size_t)(rowb + r) * 4096 + n] = z4[r];
}

// ---------------- per-timestep h-GEMM, counted-vmcnt pipeline ----------------
// grid = 512: rg = bid>>7 (32 batch rows), cg = bid&127 (32 n-cols)
// 4 LDS buffers (A 4x8KB @0, B 4x8KB @32768), 3 chunks in flight,
// 4 glls/wave/chunk -> waits 8,8,8,8,8,8,4,0.

__global__ __launch_bounds__(256) void lstm_step3(
    const float* __restrict__ Zxt,           // [128][4096] f32, this step
    const unsigned short* __restrict__ Whi,  // [4096][1024] bf16
    const float* __restrict__ bfp, const float* __restrict__ bip,
    const float* __restrict__ bgp, const float* __restrict__ bop,
    const unsigned short* __restrict__ h_prev,  // [128][1024] bf16
    unsigned short* __restrict__ h_next,        // [128][1024] bf16
    float* __restrict__ c_ws,                   // [128][1024] f32
    float* __restrict__ out, int t) {
    __shared__ __align__(16) unsigned char smem[65536];

    const int tid = threadIdx.x;
    const int l = tid & 63;
    const int w = tid >> 6;
    const int wr = w >> 1, wc = w & 1;
    const int rg = blockIdx.x >> 7;
    const int cg = blockIdx.x & 127;
    const int lq = l >> 4, sp = l & 15;
    const int g0 = l & 3;
    const int n = cg * 32 + wc * 16 + sp;
    const int j = n >> 2;
    const int j0 = cg * 8 + wc * 4;
    const int cidx = sp >> 2;
    const int srcb = l & 48;
    const int rbase = rg * 32 + wr * 16 + lq * 4;

    // epilogue operands issued BEFORE prologue glls (in-order vmcnt retire
    // keeps the counted waits valid)
    const float biasv = (g0 == 0) ? bfp[j] : (g0 == 1) ? bip[j]
                      : (g0 == 2) ? bgp[j] : bop[j];
    float zx0 = Zxt[(size_t)(rbase + 0) * 4096 + n];
    float zx1 = Zxt[(size_t)(rbase + 1) * 4096 + n];
    float zx2 = Zxt[(size_t)(rbase + 2) * 4096 + n];
    float zx3 = Zxt[(size_t)(rbase + 3) * 4096 + n];
    float cp0 = c_ws[(size_t)(rbase + 0) * 1024 + j];
    float cp1 = c_ws[(size_t)(rbase + 1) * 1024 + j];
    float cp2 = c_ws[(size_t)(rbase + 2) * 1024 + j];
    float cp3 = c_ws[(size_t)(rbase + 3) * 1024 + j];

    f32x4 acc_a = {0.f, 0.f, 0.f, 0.f};
    f32x4 acc_b = {0.f, 0.f, 0.f, 0.f};

    const int bn0 = w * 8 + lq, bn1 = bn0 + 4;
    const unsigned short* hsrc0 = h_prev + (size_t)(rg * 32 + bn0) * 1024 + (sp ^ (bn0 & 7)) * 8;
    const unsigned short* hsrc1 = h_prev + (size_t)(rg * 32 + bn1) * 1024 + (sp ^ (bn1 & 7)) * 8;
    const unsigned short* wsrc0 = Whi + (size_t)(cg * 32 + bn0) * 1024 + (sp ^ (bn0 & 7)) * 8;
    const unsigned short* wsrc1 = Whi + (size_t)(cg * 32 + bn1) * 1024 + (sp ^ (bn1 & 7)) * 8;

    auto stage = [&](int c, int buf) {  // 4 glls/wave: 2 A (h) + 2 B (Wh)
        unsigned char* Ab = smem + buf * 8192;
        unsigned char* Bb = smem + 32768 + buf * 8192;
        gll16(hsrc0 + c * 128, Ab + (w * 8) * 256);
        gll16(hsrc1 + c * 128, Ab + (w * 8 + 4) * 256);
        gll16(wsrc0 + c * 128, Bb + (w * 8) * 256);
        gll16(wsrc1 + c * 128, Bb + (w * 8 + 4) * 256);
    };
    auto compute = [&](int buf) {
        const unsigned char* Ab = smem + buf * 8192;
        const unsigned char* Bb = smem + 32768 + buf * 8192;
        const int ar = wr * 16 + sp;
        const int br = wc * 16 + sp;
        const unsigned abase = (unsigned)(ar * 256), axor = (unsigned)((ar & 7) << 4);
        const unsigned bbase = (unsigned)(br * 256), bxor = (unsigned)((br & 7) << 4);
#pragma unroll
        for (int ks = 0; ks < 4; ++ks) {
            const unsigned kk2 = (unsigned)((ks * 4 + lq) << 4);
            short8 a = *(const short8*)(Ab + abase + (kk2 ^ axor));
            short8 b = *(const short8*)(Bb + bbase + (kk2 ^ bxor));
            if (ks & 1) acc_b = __builtin_amdgcn_mfma_f32_16x16x32_bf16(a, b, acc_b, 0, 0, 0);
            else        acc_a = __builtin_amdgcn_mfma_f32_16x16x32_bf16(a, b, acc_a, 0, 0, 0);
        }
    };

    // prologue: 3 chunks in flight
    stage(0, 0); stage(1, 1); stage(2, 2);

#define PH(c, WN, DO_STAGE)                                                   \
    asm volatile("s_waitcnt vmcnt(" #WN ") lgkmcnt(0)" ::: "memory");         \
    __builtin_amdgcn_sched_barrier(0);                                        \
    __builtin_amdgcn_s_barrier();                                             \
    if (DO_STAGE) stage((c) + 3, ((c) + 3) & 3);                              \
    compute((c) & 3);

    PH(0, 8, 1)
    PH(1, 8, 1)
    PH(2, 8, 1)
    PH(3, 8, 1)
    PH(4, 8, 1)
    PH(5, 8, 0)
    PH(6, 4, 0)
    PH(7, 0, 0)
#undef PH

    // epilogue: z = zh + zx + bias; gates via lane-xor; 4x4 transpose stores
    f32x4 z4 = acc_a + acc_b;
    z4[0] += zx0 + biasv; z4[1] += zx1 + biasv;
    z4[2] += zx2 + biasv; z4[3] += zx3 + biasv;
    float cpv[4] = {cp0, cp1, cp2, cp3};
    float hhv[4], ccv[4];
#pragma unroll
    for (int r = 0; r < 4; ++r) {
        float z = z4[r];
        float v1 = __shfl_xor(z, 1);
        float v2 = __shfl_xor(z, 2);
        float v3 = __shfl_xor(z, 3);
        float fg = fsig(z);     // meaningful in g0==0 lanes
        float ig = fsig(v1);
        float gg = ftanh(v2);
        float og = fsig(v3);
        float cc = fg * cpv[r] + ig * gg;
        ccv[r] = cc;
        hhv[r] = og * ftanh(cc);
    }
#pragma unroll
    for (int r = 0; r < 4; ++r) {
        float e0 = __shfl(hhv[r], srcb + 0);
        float e1 = __shfl(hhv[r], srcb + 4);
        float e2 = __shfl(hhv[r], srcb + 8);
        float e3 = __shfl(hhv[r], srcb + 12);
        float d0 = __shfl(ccv[r], srcb + 0);
        float d1 = __shfl(ccv[r], srcb + 4);
        float d2 = __shfl(ccv[r], srcb + 8);
        float d3 = __shfl(ccv[r], srcb + 12);
        if (g0 == 0 && cidx == r) {
            const int row = rbase + r;
            float4 o4; o4.x = e0; o4.y = e1; o4.z = e2; o4.w = e3;
            float4 q4; q4.x = d0; q4.y = d1; q4.z = d2; q4.w = d3;
            *(float4*)(&out[((size_t)t * BB + row) * 1024 + j0]) = o4;
            *(float4*)(&c_ws[(size_t)row * 1024 + j0]) = q4;
            uint2 h2;
            h2.x = (unsigned)f2bf(e0) | ((unsigned)f2bf(e1) << 16);
            h2.y = (unsigned)f2bf(e2) | ((unsigned)f2bf(e3) << 16);
            *(uint2*)(&h_next[(size_t)row * 1024 + j0]) = h2;
            if (t == TT - 1) {
                *(float4*)(&out[(size_t)TT * BB * 1024 + (size_t)row * 1024 + j0]) = o4;
                *(float4*)(&out[(size_t)TT * BB * 1024 + (size_t)BB * 1024 +
                                (size_t)row * 1024 + j0]) = q4;
            }
        }
    }
}

// ---------------- host ----------------

extern "C" void kernel_launch(void* const* d_in, const int* in_sizes, int n_in,
                              void* d_out, int out_size, void* d_ws, size_t ws_size,
                              hipStream_t stream) {
    const float* X  = (const float*)d_in[0];
    const float* Wf = (const float*)d_in[1];
    const float* bf = (const float*)d_in[2];
    const float* Wi = (const float*)d_in[3];
    const float* bi = (const float*)d_in[4];
    const float* Wg = (const float*)d_in[5];
    const float* bg = (const float*)d_in[6];
    const float* Wo = (const float*)d_in[7];
    const float* bo = (const float*)d_in[8];
    unsigned char* ws = (unsigned char*)d_ws;

    unsigned short* Wxi = (unsigned short*)(ws + WX_OFF);
    unsigned short* Whi = (unsigned short*)(ws + WH_OFF);
    unsigned short* hbuf = (unsigned short*)(ws + H_OFF);
    float* c_ws = (float*)(ws + C_OFF);
    float* Zx = (float*)(ws + ZX_OFF);
    float* outp = (float*)d_out;

    // adaptive Zx chunk length (deterministic in ws_size)
    int C = 4;
    const int cands[8] = {512, 256, 128, 64, 32, 16, 8, 4};
    for (int i = 0; i < 8; ++i) {
        if ((size_t)ZX_OFF + (size_t)cands[i] * 2097152u <= ws_size) { C = cands[i]; break; }
    }

    cvt_wi<<<dim3(4096), dim3(256), 0, stream>>>(Wf, Wi, Wg, Wo, Wxi, Whi);
    zero_ws<<<dim3(1024), dim3(256), 0, stream>>>((unsigned int*)(ws + H_OFF));

    const int nchunks = TT / C;
    for (int ch = 0; ch < nchunks; ++ch) {
        gemm_zx<<<dim3(C * 4 * 128), dim3(256), 0, stream>>>(
            X + (size_t)ch * C * BB * 1024, Wxi, Zx);
        for (int tl = 0; tl < C; ++tl) {
            const int t = ch * C + tl;
            const unsigned short* hp = hbuf + (size_t)(t & 1) * (BB * 1024);
            unsigned short* hn = hbuf + (size_t)((t + 1) & 1) * (BB * 1024);
            lstm_step3<<<dim3(512), dim3(256), 0, stream>>>(
                Zx + (size_t)tl * BB * 4096, Whi, bf, bi, bg, bo,
                hp, hn, c_ws, outp, t);
        }
    }
}